// Round 1
// baseline (557.952 us; speedup 1.0000x reference)
//
#include <hip/hip_runtime.h>
#include <hip/hip_bf16.h>

typedef unsigned short u16;
typedef __bf16 bf16x8_t __attribute__((ext_vector_type(8)));
typedef float f32x4_t __attribute__((ext_vector_type(4)));

struct alignas(8) us4 { u16 v[4]; };

__device__ __forceinline__ u16 f2bf(float f) {
  __hip_bfloat16 h = __float2bfloat16(f);
  u16 u; __builtin_memcpy(&u, &h, 2); return u;
}
__device__ __forceinline__ float bf2f(u16 u) {
  __hip_bfloat16 h; __builtin_memcpy(&h, &u, 2); return __bfloat162float(h);
}

#define BM 128
#define BN 128
#define BK 32
#define KPAD 40

#define M_PROJ_Q 0
#define M_PROJ_T 1
#define M_PLAIN  2
#define M_OUT    3
#define M_FINAL  4

// Generic bf16 MFMA GEMM: C[m][n] = sum_k A[m][k] * BT[n][k]
// A row-major [M][lda] (fp32 if AF32, else bf16), BT row-major [N][ldb] bf16.
// 128x128 tile, BK=32, 4 waves each computing 64x64 via 4x4 16x16x32 MFMA frags.
// Epilogue layout folded per MODE.
template<int MODE, bool AF32>
__global__ __launch_bounds__(256, 2)
void gemm_kernel(const void* __restrict__ Av, long sAz, int lda,
                 const u16* __restrict__ BT, long sBz, int ldb,
                 const float* __restrict__ bias,
                 void* __restrict__ Cv, long sCz, int ldc,
                 int K)
{
  __shared__ u16 As[BM][KPAD];
  __shared__ u16 Bs[BN][KPAD];
  const int z = blockIdx.z;
  const int tid = threadIdx.x;
  const int lane = tid & 63;
  const int wave = tid >> 6;
  const int wm = (wave >> 1) * 64;
  const int wn = (wave & 1) * 64;
  const int m0 = blockIdx.y * BM;
  const int n0 = blockIdx.x * BN;
  const int r_ = tid >> 2;          // 0..63: row within half-tile
  const int kc = (tid & 3) * 8;     // 0,8,16,24: k element offset

  const float* Af = nullptr; const u16* Au = nullptr;
  if constexpr (AF32) Af = (const float*)Av + (long)z * sAz;
  else                Au = (const u16*)Av + (long)z * sAz;
  const u16* Bz = BT + (long)z * sBz;

  f32x4_t acc[4][4];
#pragma unroll
  for (int i = 0; i < 4; i++)
#pragma unroll
    for (int j = 0; j < 4; j++) acc[i][j] = (f32x4_t){0.f, 0.f, 0.f, 0.f};

  for (int k0 = 0; k0 < K; k0 += BK) {
    uint4 a0v, a1v;
    if constexpr (AF32) {
      const float* p0 = Af + (long)(m0 + r_) * lda + k0 + kc;
      const float* p1 = Af + (long)(m0 + r_ + 64) * lda + k0 + kc;
      float4 f00 = *(const float4*)p0;
      float4 f01 = *(const float4*)(p0 + 4);
      float4 f10 = *(const float4*)p1;
      float4 f11 = *(const float4*)(p1 + 4);
      u16 t0[8] = {f2bf(f00.x), f2bf(f00.y), f2bf(f00.z), f2bf(f00.w),
                   f2bf(f01.x), f2bf(f01.y), f2bf(f01.z), f2bf(f01.w)};
      u16 t1[8] = {f2bf(f10.x), f2bf(f10.y), f2bf(f10.z), f2bf(f10.w),
                   f2bf(f11.x), f2bf(f11.y), f2bf(f11.z), f2bf(f11.w)};
      __builtin_memcpy(&a0v, t0, 16);
      __builtin_memcpy(&a1v, t1, 16);
    } else {
      a0v = *(const uint4*)(Au + (long)(m0 + r_) * lda + k0 + kc);
      a1v = *(const uint4*)(Au + (long)(m0 + r_ + 64) * lda + k0 + kc);
    }
    uint4 b0v = *(const uint4*)(Bz + (long)(n0 + r_) * ldb + k0 + kc);
    uint4 b1v = *(const uint4*)(Bz + (long)(n0 + r_ + 64) * ldb + k0 + kc);
    __syncthreads();
    *(uint4*)&As[r_][kc] = a0v;
    *(uint4*)&As[r_ + 64][kc] = a1v;
    *(uint4*)&Bs[r_][kc] = b0v;
    *(uint4*)&Bs[r_ + 64][kc] = b1v;
    __syncthreads();
    const int kk = (lane >> 4) * 8;
    bf16x8_t afr[4], bfr[4];
#pragma unroll
    for (int i = 0; i < 4; i++) afr[i] = *(const bf16x8_t*)&As[wm + i * 16 + (lane & 15)][kk];
#pragma unroll
    for (int j = 0; j < 4; j++) bfr[j] = *(const bf16x8_t*)&Bs[wn + j * 16 + (lane & 15)][kk];
#pragma unroll
    for (int i = 0; i < 4; i++)
#pragma unroll
      for (int j = 0; j < 4; j++)
        acc[i][j] = __builtin_amdgcn_mfma_f32_16x16x32_bf16(afr[i], bfr[j], acc[i][j], 0, 0, 0);
  }

  // C/D frag layout (HW-verified): col = lane&15, row = (lane>>4)*4 + reg
  const int row_base = m0 + wm + ((lane >> 4) << 2);
  const int col_base = n0 + wn + (lane & 15);

  if constexpr (MODE == M_PROJ_Q) {
    // write qs[b,h,s,e] = C[m=(b,s)][n=(h,e)] + bias[n]
    u16* q_out = (u16*)Cv;
#pragma unroll
    for (int i = 0; i < 4; i++) {
      const int mr = row_base + i * 16;
      const int b = mr >> 11, s = mr & 2047;
#pragma unroll
      for (int j = 0; j < 4; j++) {
        const int gc = col_base + j * 16;
        const int h = gc >> 9, e = gc & 511;
        const float bb = bias[gc];
        const long base = (long)(b * 8 + h) * 1048576 + e;
#pragma unroll
        for (int r = 0; r < 4; r++)
          q_out[base + (long)(s + r) * 512] = f2bf(acc[i][j][r] + bb);
      }
    }
  } else if constexpr (MODE == M_PROJ_T) {
    // write transposed: T[b,h,e,s] = C[m=(b,s)][n=(h,e)] + bias[n]; 4 consecutive s -> us4
    u16* t_out = (u16*)Cv;
#pragma unroll
    for (int i = 0; i < 4; i++) {
      const int mr = row_base + i * 16;
      const int b = mr >> 11, s = mr & 2047;
#pragma unroll
      for (int j = 0; j < 4; j++) {
        const int gc = col_base + j * 16;
        const int h = gc >> 9, e = gc & 511;
        const float bb = bias[gc];
        us4 w;
#pragma unroll
        for (int r = 0; r < 4; r++) w.v[r] = f2bf(acc[i][j][r] + bb);
        *(us4*)&t_out[(long)(b * 8 + h) * 1048576 + (long)e * 2048 + s] = w;
      }
    }
  } else if constexpr (MODE == M_PLAIN) {
    u16* C = (u16*)Cv + (long)z * sCz;
#pragma unroll
    for (int i = 0; i < 4; i++)
#pragma unroll
      for (int j = 0; j < 4; j++)
#pragma unroll
        for (int r = 0; r < 4; r++)
          C[(long)(row_base + i * 16 + r) * ldc + col_base + j * 16] = f2bf(acc[i][j][r]);
  } else if constexpr (MODE == M_OUT) {
    // z = b*8+h; write out2[(b*2048+s)*4096 + j*8 + h]  (rearrange d outer, h inner)
    u16* o = (u16*)Cv;
    const int b2 = z >> 3, h = z & 7;
    const long ob = (long)b2 * 2048 * 4096 + h;
#pragma unroll
    for (int i = 0; i < 4; i++)
#pragma unroll
      for (int j = 0; j < 4; j++)
#pragma unroll
        for (int r = 0; r < 4; r++)
          o[ob + (long)(row_base + i * 16 + r) * 4096 + (long)(col_base + j * 16) * 8] =
              f2bf(acc[i][j][r]);
  } else { // M_FINAL: fp32 out + bias
    float* o = (float*)Cv;
#pragma unroll
    for (int i = 0; i < 4; i++)
#pragma unroll
      for (int j = 0; j < 4; j++) {
        const int gc = col_base + j * 16;
        const float bb = bias[gc];
#pragma unroll
        for (int r = 0; r < 4; r++)
          o[(long)(row_base + i * 16 + r) * ldc + gc] = acc[i][j][r] + bb;
      }
  }
}

// Batched transpose+convert: out[z][c][r] = bf16(in[z][r][c]); in fp32 [z][R][C]
__global__ void tcvt_kernel(const float* __restrict__ in, u16* __restrict__ out,
                            int R, int C)
{
  __shared__ float tile[32][33];
  const long zoff = (long)blockIdx.z * R * C;
  const float* inz = in + zoff;
  u16* outz = out + zoff;
  const int c0 = blockIdx.x * 32, r0 = blockIdx.y * 32;
#pragma unroll
  for (int yy = threadIdx.y; yy < 32; yy += 8)
    tile[yy][threadIdx.x] = inz[(long)(r0 + yy) * C + c0 + threadIdx.x];
  __syncthreads();
#pragma unroll
  for (int yy = threadIdx.y; yy < 32; yy += 8)
    outz[(long)(c0 + yy) * R + r0 + threadIdx.x] = f2bf(tile[threadIdx.x][yy]);
}

// Softmax over the 8 heads: t layout [b][h][inner], h-stride = 1048576, b = blockIdx.y
__global__ void softmax8_kernel(u16* __restrict__ t)
{
  const long HS = 1048576;
  const long i = ((long)blockIdx.x * 256 + threadIdx.x) * 4;
  u16* base = t + (long)blockIdx.y * 8 * HS + i;
  float v[8][4];
#pragma unroll
  for (int h = 0; h < 8; h++) {
    us4 u = *(const us4*)(base + h * HS);
#pragma unroll
    for (int c = 0; c < 4; c++) v[h][c] = bf2f(u.v[c]);
  }
#pragma unroll
  for (int c = 0; c < 4; c++) {
    float m = v[0][c];
#pragma unroll
    for (int h = 1; h < 8; h++) m = fmaxf(m, v[h][c]);
    float ssum = 0.f;
#pragma unroll
    for (int h = 0; h < 8; h++) { v[h][c] = __expf(v[h][c] - m); ssum += v[h][c]; }
    const float inv = 1.f / ssum;
#pragma unroll
    for (int h = 0; h < 8; h++) v[h][c] *= inv;
  }
#pragma unroll
  for (int h = 0; h < 8; h++) {
    us4 w;
#pragma unroll
    for (int c = 0; c < 4; c++) w.v[c] = f2bf(v[h][c]);
    *(us4*)(base + h * HS) = w;
  }
}

extern "C" void kernel_launch(void* const* d_in, const int* in_sizes, int n_in,
                              void* d_out, int out_size, void* d_ws, size_t ws_size,
                              hipStream_t stream) {
  const float* q  = (const float*)d_in[0];
  const float* k  = (const float*)d_in[1];
  const float* v  = (const float*)d_in[2];
  const float* Wq = (const float*)d_in[3];
  const float* bq = (const float*)d_in[4];
  const float* Wk = (const float*)d_in[5];
  const float* bk = (const float*)d_in[6];
  const float* Wv = (const float*)d_in[7];
  const float* bv = (const float*)d_in[8];
  const float* Wo = (const float*)d_in[9];
  const float* bo = (const float*)d_in[10];
  float* outp = (float*)d_out;

  char* ws = (char*)d_ws;
  // layout (bytes):
  u16* WqT  = (u16*)(ws + (0L << 20));    //  4 MiB  [h*512+e][d]
  u16* WkT  = (u16*)(ws + (4L << 20));    //  4 MiB
  u16* WvT  = (u16*)(ws + (8L << 20));    //  4 MiB
  u16* WoT  = (u16*)(ws + (12L << 20));   //  4 MiB  [n][j*8+h]
  u16* ctxT = (u16*)(ws + (16L << 20));   // 16 MiB  [b,h][e][d]
  u16* qs   = (u16*)(ws + (32L << 20));   // 64 MiB  [b,h,s,e]
  u16* vsT  = (u16*)(ws + (96L << 20));   // 64 MiB  [b,h,e,s]
  u16* ksT  = (u16*)(ws + (160L << 20));  // 64 MiB  [b,h,e,s]; reused as out2 after ctx GEMM
  u16* out2 = ksT;                        // [b,s,(j*8+h)]

  dim3 tb(32, 8, 1);
  // weight transposes: WT[h*512+e][d] = W[h][d][e]; WoT[n][k] = Wo[k][n]
  tcvt_kernel<<<dim3(16, 16, 8), tb, 0, stream>>>(Wq, WqT, 512, 512);
  tcvt_kernel<<<dim3(16, 16, 8), tb, 0, stream>>>(Wk, WkT, 512, 512);
  tcvt_kernel<<<dim3(16, 16, 8), tb, 0, stream>>>(Wv, WvT, 512, 512);
  tcvt_kernel<<<dim3(16, 128, 1), tb, 0, stream>>>(Wo, WoT, 4096, 512);

  // projections: M=8192, N=4096, K=512
  gemm_kernel<M_PROJ_Q, true><<<dim3(32, 64, 1), 256, 0, stream>>>(
      q, 0, 512, WqT, 0, 512, bq, qs, 0, 0, 512);
  gemm_kernel<M_PROJ_T, true><<<dim3(32, 64, 1), 256, 0, stream>>>(
      k, 0, 512, WkT, 0, 512, bk, ksT, 0, 0, 512);
  gemm_kernel<M_PROJ_T, true><<<dim3(32, 64, 1), 256, 0, stream>>>(
      v, 0, 512, WvT, 0, 512, bv, vsT, 0, 0, 512);

  // softmax over heads (both layouts have h-stride 1048576 within b)
  softmax8_kernel<<<dim3(1024, 4, 1), 256, 0, stream>>>(qs);
  softmax8_kernel<<<dim3(1024, 4, 1), 256, 0, stream>>>(ksT);

  // ctxT[b,h][e][d] = sum_s vsT[e][s] * ksT[d][s];  M=N=512, K=2048, batch 32
  gemm_kernel<M_PLAIN, false><<<dim3(4, 4, 32), 256, 0, stream>>>(
      vsT, 1048576, 2048, ksT, 1048576, 2048, nullptr, ctxT, 262144, 512, 2048);

  // out2[(b,s),(j,h)] = sum_d qs[s][d] * ctxT[j][d];  M=2048, N=512, K=512, batch 32
  gemm_kernel<M_OUT, false><<<dim3(4, 16, 32), 256, 0, stream>>>(
      qs, 1048576, 512, ctxT, 262144, 512, nullptr, out2, 0, 0, 512);

  // final = out2 @ Wo + bo; M=8192, N=512, K=4096, fp32 out
  gemm_kernel<M_FINAL, false><<<dim3(4, 64, 1), 256, 0, stream>>>(
      out2, 0, 4096, WoT, 0, 4096, bo, outp, 0, 512, 4096);
}

// Round 3
// 383.493 us; speedup vs baseline: 1.4549x; 1.4549x over previous
//
#include <hip/hip_runtime.h>
#include <hip/hip_bf16.h>

typedef unsigned short u16;
typedef __bf16 bf16x8_t __attribute__((ext_vector_type(8)));
typedef float f32x4_t __attribute__((ext_vector_type(4)));

struct alignas(8) us4 { u16 v[4]; };

__device__ __forceinline__ u16 f2bf(float f) {
  __hip_bfloat16 h = __float2bfloat16(f);
  u16 u; __builtin_memcpy(&u, &h, 2); return u;
}
__device__ __forceinline__ float bf2f(u16 u) {
  __hip_bfloat16 h; __builtin_memcpy(&h, &u, 2); return __bfloat162float(h);
}

__device__ __forceinline__ void gload16(const u16* g, u16* l) {
  __builtin_amdgcn_global_load_lds(
      (const __attribute__((address_space(1))) void*)g,
      (__attribute__((address_space(3))) void*)l, 16, 0, 0);
}

#define M_PROJ_Q 0
#define M_PROJ_T 1
#define M_PLAIN  2
#define M_OUT    3
#define M_FINAL  4

// C[m][n] = sum_k A[m][k] * BT[n][k], all bf16, 128x128 tile, BK=32.
// global_load_lds width-16 staging into linear LDS [128][32] (m97 structure).
// Epilogue: LDS-staged coalesced writes, layout folded per MODE.
// 1D grid with XCD-bijective swizzle; grid = nx*ny*nz.
template<int MODE>
__global__ __launch_bounds__(256, 2)
void gemm_kernel(const u16* __restrict__ A, long sAz, int lda,
                 const u16* __restrict__ B, long sBz, int ldb,
                 const float* __restrict__ bias,
                 void* __restrict__ Cv, long sCz, int ldc,
                 int nx, int K)
{
  __shared__ __align__(16) u16 smem[17408];  // 34816 B; As/Bs then reused as Cs
  u16* As = smem;          // [128][32] linear
  u16* Bs = smem + 4096;   // [128][32] linear

  // XCD-bijective swizzle (gridDim.x % 8 == 0 for all launches here)
  const int nwg = gridDim.x;
  const int chunk = nwg >> 3;
  const int bid = blockIdx.x;
  const int wg = (bid & 7) * chunk + (bid >> 3);
  const int nxy = nx * ((MODE == M_PLAIN) ? 4 : (MODE == M_OUT ? 16 : 64));
  const int z = wg / nxy;
  const int rem = wg - z * nxy;
  const int by = rem / nx;
  const int bx = rem - by * nx;

  const int tid = threadIdx.x;
  const int lane = tid & 63;
  const int wave = tid >> 6;
  const int wm = (wave >> 1) * 64;
  const int wn = (wave & 1) * 64;
  const int m0 = by * 128;
  const int n0 = bx * 128;

  const u16* Az = A + (long)z * sAz;
  const u16* Bz = B + (long)z * sBz;

  // staging addresses: thread t stages 16B chunks t and t+256 (A and B each)
  const int srow = tid >> 2;            // 0..63
  const int scol = (tid & 3) * 8;       // 0,8,16,24
  const u16* aptr0 = Az + (long)(m0 + srow) * lda + scol;
  const u16* aptr1 = aptr0 + (long)64 * lda;
  const u16* bptr0 = Bz + (long)(n0 + srow) * ldb + scol;
  const u16* bptr1 = bptr0 + (long)64 * ldb;
  u16* lA0 = As + tid * 8;
  u16* lA1 = As + (tid + 256) * 8;
  u16* lB0 = Bs + tid * 8;
  u16* lB1 = Bs + (tid + 256) * 8;

  f32x4_t acc[4][4];
#pragma unroll
  for (int i = 0; i < 4; i++)
#pragma unroll
    for (int j = 0; j < 4; j++) acc[i][j] = (f32x4_t){0.f, 0.f, 0.f, 0.f};

  const int kk = (lane >> 4) * 8;
  const int fr = lane & 15;

  for (int k0 = 0; k0 < K; k0 += 32) {
    gload16(aptr0 + k0, lA0);
    gload16(aptr1 + k0, lA1);
    gload16(bptr0 + k0, lB0);
    gload16(bptr1 + k0, lB1);
    __syncthreads();  // drains vmcnt -> LDS tile valid
    bf16x8_t afr[4], bfr[4];
#pragma unroll
    for (int i = 0; i < 4; i++) afr[i] = *(const bf16x8_t*)&As[(wm + i * 16 + fr) * 32 + kk];
#pragma unroll
    for (int j = 0; j < 4; j++) bfr[j] = *(const bf16x8_t*)&Bs[(wn + j * 16 + fr) * 32 + kk];
#pragma unroll
    for (int i = 0; i < 4; i++)
#pragma unroll
      for (int j = 0; j < 4; j++)
        acc[i][j] = __builtin_amdgcn_mfma_f32_16x16x32_bf16(afr[i], bfr[j], acc[i][j], 0, 0, 0);
    __syncthreads();  // all reads done before next overwrite
  }

  // C/D frag layout: col = lane&15 (+wn+j*16), row = (lane>>4)*4 + reg (+wm+i*16)
  if constexpr (MODE == M_FINAL) {
    // direct fp32 writes: 16 consecutive floats per 16-lane group = full 64B lines
    float* o = (float*)Cv;
#pragma unroll
    for (int i = 0; i < 4; i++) {
      const int rbase = m0 + wm + i * 16 + ((lane >> 4) << 2);
#pragma unroll
      for (int j = 0; j < 4; j++) {
        const int gc = n0 + wn + j * 16 + fr;
        const float bb = bias[gc];
#pragma unroll
        for (int r = 0; r < 4; r++)
          o[(long)(rbase + r) * ldc + gc] = acc[i][j][r] + bb;
      }
    }
    return;
  }

  // LDS-staged epilogue: Cs[128][136] (pad 8 elems = 16B)
  u16* Cs = smem;
  if constexpr (MODE == M_PROJ_T) {
    // tile transposed: Cs[row=n(e)][col=m(s)], us4 along s
#pragma unroll
    for (int j = 0; j < 4; j++) {
      const int e = wn + j * 16 + fr;
      const float bb = bias[n0 + e];
#pragma unroll
      for (int i = 0; i < 4; i++) {
        us4 w;
#pragma unroll
        for (int r = 0; r < 4; r++) w.v[r] = f2bf(acc[i][j][r] + bb);
        *(us4*)&Cs[e * 136 + wm + i * 16 + ((lane >> 4) << 2)] = w;
      }
    }
  } else {
    constexpr bool HB = (MODE == M_PROJ_Q);
#pragma unroll
    for (int j = 0; j < 4; j++) {
      const int cn = wn + j * 16 + fr;
      const float bb = HB ? bias[n0 + cn] : 0.f;
#pragma unroll
      for (int i = 0; i < 4; i++) {
        const int rbase = wm + i * 16 + ((lane >> 4) << 2);
#pragma unroll
        for (int r = 0; r < 4; r++)
          Cs[(rbase + r) * 136 + cn] = f2bf(acc[i][j][r] + bb);
      }
    }
  }
  __syncthreads();

  // coalesced copy-out: 128 rows x 128 u16 = 2048 16B-chunks -> 8 iters x 256 thr
  u16* dst = (u16*)Cv;
  long base; int rs;
  if constexpr (MODE == M_PROJ_Q) {
    const int b = m0 >> 11, s0 = m0 & 2047, h = n0 >> 9, e0 = n0 & 511;
    base = (long)(b * 8 + h) * 1048576 + (long)s0 * 512 + e0; rs = 512;
  } else if constexpr (MODE == M_PROJ_T) {
    const int b = m0 >> 11, s0 = m0 & 2047, h = n0 >> 9, e0 = n0 & 511;
    base = (long)(b * 8 + h) * 1048576 + (long)e0 * 2048 + s0; rs = 2048;
  } else if constexpr (MODE == M_PLAIN) {
    base = (long)z * sCz + (long)m0 * ldc + n0; rs = ldc;
  } else {  // M_OUT: out2[b][s][h*512 + j]
    const int b = z >> 3, h = z & 7;
    base = ((long)b * 2048 + m0) * 4096 + h * 512 + n0; rs = 4096;
  }
#pragma unroll
  for (int it = 0; it < 8; it++) {
    const int idx = it * 256 + tid;
    const int row = idx >> 4, ch = idx & 15;
    *(uint4*)&dst[base + (long)row * rs + ch * 8] = *(const uint4*)&Cs[row * 136 + ch * 8];
  }
}

// fp32 -> bf16 vectorized convert
__global__ void cvt_kernel(const float* __restrict__ in, u16* __restrict__ out) {
  const long i = ((long)blockIdx.x * 256 + threadIdx.x) * 8;
  float4 a = *(const float4*)(in + i);
  float4 b = *(const float4*)(in + i + 4);
  u16 t[8] = {f2bf(a.x), f2bf(a.y), f2bf(a.z), f2bf(a.w),
              f2bf(b.x), f2bf(b.y), f2bf(b.z), f2bf(b.w)};
  uint4 w; __builtin_memcpy(&w, t, 16);
  *(uint4*)(out + i) = w;
}

// Batched transpose+convert: out[z][c][r] = bf16(in[z][r][c]); in fp32 [z][R][C]
__global__ void tcvt_kernel(const float* __restrict__ in, u16* __restrict__ out,
                            int R, int C)
{
  __shared__ float tile[32][33];
  const long zoff = (long)blockIdx.z * R * C;
  const float* inz = in + zoff;
  u16* outz = out + zoff;
  const int c0 = blockIdx.x * 32, r0 = blockIdx.y * 32;
#pragma unroll
  for (int yy = threadIdx.y; yy < 32; yy += 8)
    tile[yy][threadIdx.x] = inz[(long)(r0 + yy) * C + c0 + threadIdx.x];
  __syncthreads();
#pragma unroll
  for (int yy = threadIdx.y; yy < 32; yy += 8)
    outz[(long)(c0 + yy) * R + r0 + threadIdx.x] = f2bf(tile[threadIdx.x][yy]);
}

// WoT[f][c] = bf16(Wo[(c&511)*8 + (c>>9)][f]); Wo [4096][512] fp32, WoT [512][4096]
__global__ void tcvt_wo(const float* __restrict__ in, u16* __restrict__ out) {
  __shared__ float tile[32][33];
  const int c0 = blockIdx.x * 32, f0 = blockIdx.y * 32;
  const int h = c0 >> 9, j0 = c0 & 511;
#pragma unroll
  for (int yy = threadIdx.y; yy < 32; yy += 8)
    tile[yy][threadIdx.x] = in[(long)((j0 + yy) * 8 + h) * 512 + f0 + threadIdx.x];
  __syncthreads();
#pragma unroll
  for (int yy = threadIdx.y; yy < 32; yy += 8)
    out[(long)(f0 + yy) * 4096 + c0 + threadIdx.x] = f2bf(tile[threadIdx.x][yy]);
}

// Softmax over 8 heads: t layout [b][h][inner], h-stride 1048576, b = blockIdx.y
__global__ void softmax8_kernel(u16* __restrict__ t)
{
  const long HS = 1048576;
  const long i = ((long)blockIdx.x * 256 + threadIdx.x) * 4;
  u16* base = t + (long)blockIdx.y * 8 * HS + i;
  float v[8][4];
#pragma unroll
  for (int h = 0; h < 8; h++) {
    us4 u = *(const us4*)(base + h * HS);
#pragma unroll
    for (int c = 0; c < 4; c++) v[h][c] = bf2f(u.v[c]);
  }
#pragma unroll
  for (int c = 0; c < 4; c++) {
    float m = v[0][c];
#pragma unroll
    for (int h = 1; h < 8; h++) m = fmaxf(m, v[h][c]);
    float ssum = 0.f;
#pragma unroll
    for (int h = 0; h < 8; h++) { v[h][c] = __expf(v[h][c] - m); ssum += v[h][c]; }
    const float inv = 1.f / ssum;
#pragma unroll
    for (int h = 0; h < 8; h++) v[h][c] *= inv;
  }
#pragma unroll
  for (int h = 0; h < 8; h++) {
    us4 w;
#pragma unroll
    for (int c = 0; c < 4; c++) w.v[c] = f2bf(v[h][c]);
    *(us4*)(base + h * HS) = w;
  }
}

extern "C" void kernel_launch(void* const* d_in, const int* in_sizes, int n_in,
                              void* d_out, int out_size, void* d_ws, size_t ws_size,
                              hipStream_t stream) {
  const float* q  = (const float*)d_in[0];
  const float* k  = (const float*)d_in[1];
  const float* v  = (const float*)d_in[2];
  const float* Wq = (const float*)d_in[3];
  const float* bq = (const float*)d_in[4];
  const float* Wk = (const float*)d_in[5];
  const float* bk = (const float*)d_in[6];
  const float* Wv = (const float*)d_in[7];
  const float* bv = (const float*)d_in[8];
  const float* Wo = (const float*)d_in[9];
  const float* bo = (const float*)d_in[10];
  float* outp = (float*)d_out;

  char* ws = (char*)d_ws;
  // time-aliased layout (peak 212 MiB):
  u16* qs   = (u16*)(ws);                  //   0- 64 MiB [b,h,s,e]       live proj..out
  u16* WqT  = (u16*)(ws + (64L  << 20));   //  64- 68     dead before ksT written
  u16* qb   = (u16*)(ws + (72L  << 20));   //  72- 80     dead before ksT written
  u16* ksT  = (u16*)(ws + (64L  << 20));   //  64-128 [b,h,e,s]; later out2
  u16* out2 = ksT;                         //  64-128 [b,s,(h*512+j)]
  u16* kb   = (u16*)(ws + (128L << 20));   // 128-136     dead before vsT written
  u16* vsT  = (u16*)(ws + (128L << 20));   // 128-192 [b,h,e,s]
  u16* vb   = (u16*)(ws + (192L << 20));   // 192-200     dead before ctxT written
  u16* WkT  = (u16*)(ws + (200L << 20));   // 200-204     dead before ctxT written
  u16* WvT  = (u16*)(ws + (204L << 20));   // 204-208     dead before ctxT written
  u16* ctxT = (u16*)(ws + (192L << 20));   // 192-208 [b,h][e][d]
  u16* WoT  = (u16*)(ws + (208L << 20));   // 208-212 [f][h*512+j]

  // 1. fp32 -> bf16 inputs
  cvt_kernel<<<2048, 256, 0, stream>>>(q, qb);
  cvt_kernel<<<2048, 256, 0, stream>>>(k, kb);
  cvt_kernel<<<2048, 256, 0, stream>>>(v, vb);

  // 2. weight transposes
  dim3 tb(32, 8, 1);
  tcvt_kernel<<<dim3(16, 16, 8), tb, 0, stream>>>(Wq, WqT, 512, 512);
  tcvt_kernel<<<dim3(16, 16, 8), tb, 0, stream>>>(Wk, WkT, 512, 512);
  tcvt_kernel<<<dim3(16, 16, 8), tb, 0, stream>>>(Wv, WvT, 512, 512);
  tcvt_wo<<<dim3(128, 16, 1), tb, 0, stream>>>(Wo, WoT);

  // 3-5. projections: M=8192, N=4096, K=512; grid 32x64 = 2048
  gemm_kernel<M_PROJ_Q><<<2048, 256, 0, stream>>>(
      qb, 0, 512, WqT, 0, 512, bq, qs, 0, 0, 32, 512);
  gemm_kernel<M_PROJ_T><<<2048, 256, 0, stream>>>(
      kb, 0, 512, WkT, 0, 512, bk, ksT, 0, 0, 32, 512);
  gemm_kernel<M_PROJ_T><<<2048, 256, 0, stream>>>(
      vb, 0, 512, WvT, 0, 512, bv, vsT, 0, 0, 32, 512);

  // 6. softmax over heads
  softmax8_kernel<<<dim3(1024, 4, 1), 256, 0, stream>>>(qs);
  softmax8_kernel<<<dim3(1024, 4, 1), 256, 0, stream>>>(ksT);

  // 7. ctxT[b,h][e][d] = sum_s vsT[e][s]*ksT[d][s]; nx=4, ny=4, nz=32 -> 512
  gemm_kernel<M_PLAIN><<<512, 256, 0, stream>>>(
      vsT, 1048576, 2048, ksT, 1048576, 2048, nullptr, ctxT, 262144, 512, 4, 2048);

  // 8. out2[b][s][h*512+j] = sum_d qs[s][d]*ctxT[j][d]; nx=4, ny=16, nz=32 -> 2048
  gemm_kernel<M_OUT><<<2048, 256, 0, stream>>>(
      qs, 1048576, 512, ctxT, 262144, 512, nullptr, out2, 0, 0, 4, 512);

  // 9. final = out2 @ WoT^T + bo; M=8192, N=512, K=4096; nx=4, ny=64 -> 256
  gemm_kernel<M_FINAL><<<256, 256, 0, stream>>>(
      out2, 0, 4096, WoT, 0, 4096, bo, outp, 0, 512, 4, 4096);
}

// Round 4
// 352.850 us; speedup vs baseline: 1.5813x; 1.0868x over previous
//
#include <hip/hip_runtime.h>
#include <hip/hip_bf16.h>

typedef unsigned short u16;
typedef __bf16 bf16x8_t __attribute__((ext_vector_type(8)));
typedef float f32x4_t __attribute__((ext_vector_type(4)));

struct alignas(8) us4 { u16 v[4]; };

__device__ __forceinline__ u16 f2bf(float f) {
  __hip_bfloat16 h = __float2bfloat16(f);
  u16 u; __builtin_memcpy(&u, &h, 2); return u;
}
__device__ __forceinline__ float bf2f(u16 u) {
  __hip_bfloat16 h; __builtin_memcpy(&h, &u, 2); return __bfloat162float(h);
}

__device__ __forceinline__ void gload16(const u16* g, u16* l) {
  __builtin_amdgcn_global_load_lds(
      (const __attribute__((address_space(1))) void*)g,
      (__attribute__((address_space(3))) void*)l, 16, 0, 0);
}

#define M_PROJ_Q 0
#define M_PROJ_T 1
#define M_PLAIN  2
#define M_OUT    3
#define M_FINAL  4

// C[m][n] = sum_k A[m][k] * BT[n][k], all bf16, 128x128 tile, BK=32.
// 2-phase double-buffered global_load_lds staging (T3 minimum recipe):
// per K-step: ds_read cur buffer -> issue next-tile gload into other buffer
// -> MFMA -> one __syncthreads(). Epilogue LDS-staged per MODE.
// For M_FINAL: z is a K-split chunk (sAz/sBz = chunk offset in elements),
// output fp32 partial at Cv + z*sCz, no bias.
template<int MODE>
__global__ __launch_bounds__(256, 2)
void gemm_kernel(const u16* __restrict__ A, long sAz, int lda,
                 const u16* __restrict__ B, long sBz, int ldb,
                 const float* __restrict__ bias,
                 void* __restrict__ Cv, long sCz, int ldc,
                 int nx, int K)
{
  __shared__ __align__(16) u16 smem[17408];  // 34816 B; 2x(As+Bs) dbuf, reused as Cs
  // buffer layout (u16 units): buf b at b*8192: As [0,4096), Bs [4096,8192)

  // XCD-bijective swizzle (gridDim.x % 8 == 0 for all launches here)
  const int nwg = gridDim.x;
  const int chunk = nwg >> 3;
  const int bid = blockIdx.x;
  const int wg = (bid & 7) * chunk + (bid >> 3);
  const int nxy = nx * ((MODE == M_PLAIN) ? 4 : (MODE == M_OUT ? 16 : 64));
  const int z = wg / nxy;
  const int rem = wg - z * nxy;
  const int by = rem / nx;
  const int bx = rem - by * nx;

  const int tid = threadIdx.x;
  const int lane = tid & 63;
  const int wave = tid >> 6;
  const int wm = (wave >> 1) * 64;
  const int wn = (wave & 1) * 64;
  const int m0 = by * 128;
  const int n0 = bx * 128;

  const u16* Az = A + (long)z * sAz;
  const u16* Bz = B + (long)z * sBz;

  const int srow = tid >> 2;            // 0..63
  const int scol = (tid & 3) * 8;       // 0,8,16,24
  const u16* aptr0 = Az + (long)(m0 + srow) * lda + scol;
  const u16* aptr1 = aptr0 + (long)64 * lda;
  const u16* bptr0 = Bz + (long)(n0 + srow) * ldb + scol;
  const u16* bptr1 = bptr0 + (long)64 * ldb;

  f32x4_t acc[4][4];
#pragma unroll
  for (int i = 0; i < 4; i++)
#pragma unroll
    for (int j = 0; j < 4; j++) acc[i][j] = (f32x4_t){0.f, 0.f, 0.f, 0.f};

  const int kk = (lane >> 4) * 8;
  const int fr = lane & 15;
  const int nt = K >> 5;

  // fragment LDS read offsets (u16 units, relative to buffer base)
  int aoff[4], boff[4];
#pragma unroll
  for (int i = 0; i < 4; i++) aoff[i] = (wm + i * 16 + fr) * 32 + kk;
#pragma unroll
  for (int j = 0; j < 4; j++) boff[j] = 4096 + (wn + j * 16 + fr) * 32 + kk;

  // prologue: stage tile 0 into buf 0
  {
    u16* b0 = smem;
    gload16(aptr0, b0 + tid * 8);
    gload16(aptr1, b0 + (tid + 256) * 8);
    gload16(bptr0, b0 + 4096 + tid * 8);
    gload16(bptr1, b0 + 4096 + (tid + 256) * 8);
  }
  __syncthreads();

  int cur = 0;
  for (int t = 0; t < nt - 1; t++) {
    const u16* cb = smem + cur * 8192;
    bf16x8_t afr[4], bfr[4];
#pragma unroll
    for (int i = 0; i < 4; i++) afr[i] = *(const bf16x8_t*)&cb[aoff[i]];
#pragma unroll
    for (int j = 0; j < 4; j++) bfr[j] = *(const bf16x8_t*)&cb[boff[j]];
    // issue next-tile staging into the other buffer (overlaps with MFMA)
    u16* nb = smem + (cur ^ 1) * 8192;
    const int ko = (t + 1) * 32;
    gload16(aptr0 + ko, nb + tid * 8);
    gload16(aptr1 + ko, nb + (tid + 256) * 8);
    gload16(bptr0 + ko, nb + 4096 + tid * 8);
    gload16(bptr1 + ko, nb + 4096 + (tid + 256) * 8);
#pragma unroll
    for (int i = 0; i < 4; i++)
#pragma unroll
      for (int j = 0; j < 4; j++)
        acc[i][j] = __builtin_amdgcn_mfma_f32_16x16x32_bf16(afr[i], bfr[j], acc[i][j], 0, 0, 0);
    __syncthreads();  // drains vmcnt (next tile staged) + lgkm (reads done)
    cur ^= 1;
  }
  {  // last tile: compute only
    const u16* cb = smem + cur * 8192;
    bf16x8_t afr[4], bfr[4];
#pragma unroll
    for (int i = 0; i < 4; i++) afr[i] = *(const bf16x8_t*)&cb[aoff[i]];
#pragma unroll
    for (int j = 0; j < 4; j++) bfr[j] = *(const bf16x8_t*)&cb[boff[j]];
#pragma unroll
    for (int i = 0; i < 4; i++)
#pragma unroll
      for (int j = 0; j < 4; j++)
        acc[i][j] = __builtin_amdgcn_mfma_f32_16x16x32_bf16(afr[i], bfr[j], acc[i][j], 0, 0, 0);
  }
  __syncthreads();  // all LDS reads done before Cs alias reuse

  // C/D frag layout: col = lane&15 (+wn+j*16), row = (lane>>4)*4 + reg (+wm+i*16)
  if constexpr (MODE == M_FINAL) {
    // fp32 partial (K-split chunk z), no bias
    float* o = (float*)Cv + (long)z * sCz;
#pragma unroll
    for (int i = 0; i < 4; i++) {
      const int rbase = m0 + wm + i * 16 + ((lane >> 4) << 2);
#pragma unroll
      for (int j = 0; j < 4; j++) {
        const int gc = n0 + wn + j * 16 + fr;
#pragma unroll
        for (int r = 0; r < 4; r++)
          o[(long)(rbase + r) * ldc + gc] = acc[i][j][r];
      }
    }
    return;
  }

  // LDS-staged epilogue: Cs[128][136] (pad 8 elems = 16B)
  u16* Cs = smem;
  if constexpr (MODE == M_PROJ_T) {
    // tile transposed: Cs[row=n(e)][col=m(s)], us4 along s
#pragma unroll
    for (int j = 0; j < 4; j++) {
      const int e = wn + j * 16 + fr;
      const float bb = bias[n0 + e];
#pragma unroll
      for (int i = 0; i < 4; i++) {
        us4 w;
#pragma unroll
        for (int r = 0; r < 4; r++) w.v[r] = f2bf(acc[i][j][r] + bb);
        *(us4*)&Cs[e * 136 + wm + i * 16 + ((lane >> 4) << 2)] = w;
      }
    }
  } else {
    constexpr bool HB = (MODE == M_PROJ_Q);
#pragma unroll
    for (int j = 0; j < 4; j++) {
      const int cn = wn + j * 16 + fr;
      const float bb = HB ? bias[n0 + cn] : 0.f;
#pragma unroll
      for (int i = 0; i < 4; i++) {
        const int rbase = wm + i * 16 + ((lane >> 4) << 2);
#pragma unroll
        for (int r = 0; r < 4; r++)
          Cs[(rbase + r) * 136 + cn] = f2bf(acc[i][j][r] + bb);
      }
    }
  }
  __syncthreads();

  // coalesced copy-out: 128 rows x 128 u16 = 2048 16B-chunks -> 8 iters x 256 thr
  u16* dst = (u16*)Cv;
  long base; int rs;
  if constexpr (MODE == M_PROJ_Q) {
    const int b = m0 >> 11, s0 = m0 & 2047, h = n0 >> 9, e0 = n0 & 511;
    base = (long)(b * 8 + h) * 1048576 + (long)s0 * 512 + e0; rs = 512;
  } else if constexpr (MODE == M_PROJ_T) {
    const int b = m0 >> 11, s0 = m0 & 2047, h = n0 >> 9, e0 = n0 & 511;
    base = (long)(b * 8 + h) * 1048576 + (long)e0 * 2048 + s0; rs = 2048;
  } else if constexpr (MODE == M_PLAIN) {
    base = (long)z * sCz + (long)m0 * ldc + n0; rs = ldc;
  } else {  // M_OUT: out2[b][s][h*512 + j]
    const int b = z >> 3, h = z & 7;
    base = ((long)b * 2048 + m0) * 4096 + h * 512 + n0; rs = 4096;
  }
#pragma unroll
  for (int it = 0; it < 8; it++) {
    const int idx = it * 256 + tid;
    const int row = idx >> 4, ch = idx & 15;
    *(uint4*)&dst[base + (long)row * rs + ch * 8] = *(const uint4*)&Cs[row * 136 + ch * 8];
  }
}

// merged fp32 -> bf16 convert of q,k,v (2048 blocks each)
__global__ void cvt3_kernel(const float* __restrict__ q, const float* __restrict__ k,
                            const float* __restrict__ v, u16* __restrict__ qb,
                            u16* __restrict__ kb, u16* __restrict__ vb) {
  const int arr = blockIdx.x >> 11;
  const int lb = blockIdx.x & 2047;
  const float* in = arr == 0 ? q : (arr == 1 ? k : v);
  u16* out = arr == 0 ? qb : (arr == 1 ? kb : vb);
  const long i = ((long)lb * 256 + threadIdx.x) * 8;
  float4 a = *(const float4*)(in + i);
  float4 b = *(const float4*)(in + i + 4);
  u16 t[8] = {f2bf(a.x), f2bf(a.y), f2bf(a.z), f2bf(a.w),
              f2bf(b.x), f2bf(b.y), f2bf(b.z), f2bf(b.w)};
  uint4 w; __builtin_memcpy(&w, t, 16);
  *(uint4*)(out + i) = w;
}

// merged Wq/Wk/Wv transpose+convert: out[z][c][r] = bf16(in[z][r][c]), 512x512 x8 each
__global__ void tcvt3_kernel(const float* __restrict__ Wq, const float* __restrict__ Wk,
                             const float* __restrict__ Wv, u16* __restrict__ WqT,
                             u16* __restrict__ WkT, u16* __restrict__ WvT)
{
  __shared__ float tile[32][33];
  const int arr = blockIdx.z >> 3;
  const int zz = blockIdx.z & 7;
  const float* in = arr == 0 ? Wq : (arr == 1 ? Wk : Wv);
  u16* out = arr == 0 ? WqT : (arr == 1 ? WkT : WvT);
  const long zoff = (long)zz * 262144;
  const float* inz = in + zoff;
  u16* outz = out + zoff;
  const int c0 = blockIdx.x * 32, r0 = blockIdx.y * 32;
#pragma unroll
  for (int yy = threadIdx.y; yy < 32; yy += 8)
    tile[yy][threadIdx.x] = inz[(long)(r0 + yy) * 512 + c0 + threadIdx.x];
  __syncthreads();
#pragma unroll
  for (int yy = threadIdx.y; yy < 32; yy += 8)
    outz[(long)(c0 + yy) * 512 + r0 + threadIdx.x] = f2bf(tile[threadIdx.x][yy]);
}

// WoT[f][c] = bf16(Wo[(c&511)*8 + (c>>9)][f]); Wo [4096][512] fp32, WoT [512][4096]
__global__ void tcvt_wo(const float* __restrict__ in, u16* __restrict__ out) {
  __shared__ float tile[32][33];
  const int c0 = blockIdx.x * 32, f0 = blockIdx.y * 32;
  const int h = c0 >> 9, j0 = c0 & 511;
#pragma unroll
  for (int yy = threadIdx.y; yy < 32; yy += 8)
    tile[yy][threadIdx.x] = in[(long)((j0 + yy) * 8 + h) * 512 + f0 + threadIdx.x];
  __syncthreads();
#pragma unroll
  for (int yy = threadIdx.y; yy < 32; yy += 8)
    out[(long)(f0 + yy) * 4096 + c0 + threadIdx.x] = f2bf(tile[threadIdx.x][yy]);
}

// Softmax over 8 heads for both qs and ksT: [b][h][inner], h-stride 1048576
__global__ void softmax2_kernel(u16* __restrict__ qs, u16* __restrict__ ksT)
{
  const long HS = 1048576;
  u16* t = blockIdx.z ? ksT : qs;
  const long i = ((long)blockIdx.x * 256 + threadIdx.x) * 4;
  u16* base = t + (long)blockIdx.y * 8 * HS + i;
  float v[8][4];
#pragma unroll
  for (int h = 0; h < 8; h++) {
    us4 u = *(const us4*)(base + h * HS);
#pragma unroll
    for (int c = 0; c < 4; c++) v[h][c] = bf2f(u.v[c]);
  }
#pragma unroll
  for (int c = 0; c < 4; c++) {
    float m = v[0][c];
#pragma unroll
    for (int h = 1; h < 8; h++) m = fmaxf(m, v[h][c]);
    float ssum = 0.f;
#pragma unroll
    for (int h = 0; h < 8; h++) { v[h][c] = __expf(v[h][c] - m); ssum += v[h][c]; }
    const float inv = 1.f / ssum;
#pragma unroll
    for (int h = 0; h < 8; h++) v[h][c] *= inv;
  }
#pragma unroll
  for (int h = 0; h < 8; h++) {
    us4 w;
#pragma unroll
    for (int c = 0; c < 4; c++) w.v[c] = f2bf(v[h][c]);
    *(us4*)(base + h * HS) = w;
  }
}

// sum 4 fp32 K-split partials + bias -> fp32 out; 8192x512 elems, float4
__global__ void reduce4_kernel(const float* __restrict__ p, const float* __restrict__ bo,
                               float* __restrict__ out)
{
  const long S = 8192L * 512;
  const long i4 = ((long)blockIdx.x * 256 + threadIdx.x) * 4;
  float4 a = *(const float4*)(p + i4);
  float4 b = *(const float4*)(p + S + i4);
  float4 c = *(const float4*)(p + 2 * S + i4);
  float4 d = *(const float4*)(p + 3 * S + i4);
  float4 bb = *(const float4*)(bo + (i4 & 511));
  float4 r;
  r.x = a.x + b.x + c.x + d.x + bb.x;
  r.y = a.y + b.y + c.y + d.y + bb.y;
  r.z = a.z + b.z + c.z + d.z + bb.z;
  r.w = a.w + b.w + c.w + d.w + bb.w;
  *(float4*)(out + i4) = r;
}

extern "C" void kernel_launch(void* const* d_in, const int* in_sizes, int n_in,
                              void* d_out, int out_size, void* d_ws, size_t ws_size,
                              hipStream_t stream) {
  const float* q  = (const float*)d_in[0];
  const float* k  = (const float*)d_in[1];
  const float* v  = (const float*)d_in[2];
  const float* Wq = (const float*)d_in[3];
  const float* bq = (const float*)d_in[4];
  const float* Wk = (const float*)d_in[5];
  const float* bk = (const float*)d_in[6];
  const float* Wv = (const float*)d_in[7];
  const float* bv = (const float*)d_in[8];
  const float* Wo = (const float*)d_in[9];
  const float* bo = (const float*)d_in[10];
  float* outp = (float*)d_out;

  char* ws = (char*)d_ws;
  // time-aliased layout (peak 212 MiB):
  u16* qs   = (u16*)(ws);                  //   0- 64 MiB [b,h,s,e]  live proj..M_OUT
  float* Pf = (float*)(ws);                //   0- 64 MiB fp32 K-split partials (after qs dead)
  u16* WqT  = (u16*)(ws + (64L  << 20));   //  64- 68     dead before ksT written
  u16* qb   = (u16*)(ws + (72L  << 20));   //  72- 80     dead before ksT written
  u16* ksT  = (u16*)(ws + (64L  << 20));   //  64-128 [b,h,e,s]; later out2
  u16* out2 = ksT;                         //  64-128 [b,s,(h*512+j)]
  u16* kb   = (u16*)(ws + (128L << 20));   // 128-136     dead before vsT written
  u16* vsT  = (u16*)(ws + (128L << 20));   // 128-192 [b,h,e,s]
  u16* vb   = (u16*)(ws + (192L << 20));   // 192-200     dead before ctxT written
  u16* WkT  = (u16*)(ws + (200L << 20));   // 200-204     dead before ctxT written
  u16* WvT  = (u16*)(ws + (204L << 20));   // 204-208     dead before ctxT written
  u16* ctxT = (u16*)(ws + (192L << 20));   // 192-208 [b,h][e][d]
  u16* WoT  = (u16*)(ws + (208L << 20));   // 208-212 [f][h*512+j]

  // 1. fp32 -> bf16 inputs (merged)
  cvt3_kernel<<<6144, 256, 0, stream>>>(q, k, v, qb, kb, vb);

  // 2. weight transposes (merged) + Wo
  dim3 tb(32, 8, 1);
  tcvt3_kernel<<<dim3(16, 16, 24), tb, 0, stream>>>(Wq, Wk, Wv, WqT, WkT, WvT);
  tcvt_wo<<<dim3(128, 16, 1), tb, 0, stream>>>(Wo, WoT);

  // 3-5. projections: M=8192, N=4096, K=512; grid 32x64 = 2048
  gemm_kernel<M_PROJ_Q><<<2048, 256, 0, stream>>>(
      qb, 0, 512, WqT, 0, 512, bq, qs, 0, 0, 32, 512);
  gemm_kernel<M_PROJ_T><<<2048, 256, 0, stream>>>(
      kb, 0, 512, WkT, 0, 512, bk, ksT, 0, 0, 32, 512);
  gemm_kernel<M_PROJ_T><<<2048, 256, 0, stream>>>(
      vb, 0, 512, WvT, 0, 512, bv, vsT, 0, 0, 32, 512);

  // 6. softmax over heads (merged)
  softmax2_kernel<<<dim3(1024, 4, 2), 256, 0, stream>>>(qs, ksT);

  // 7. ctxT[b,h][e][d] = sum_s vsT[e][s]*ksT[d][s]; nx=4, ny=4, nz=32 -> 512
  gemm_kernel<M_PLAIN><<<512, 256, 0, stream>>>(
      vsT, 1048576, 2048, ksT, 1048576, 2048, nullptr, ctxT, 262144, 512, 4, 2048);

  // 8. out2[b][s][h*512+j] = sum_d qs[s][d]*ctxT[j][d]; nx=4, ny=16, nz=32 -> 2048
  gemm_kernel<M_OUT><<<2048, 256, 0, stream>>>(
      qs, 1048576, 512, ctxT, 262144, 512, nullptr, out2, 0, 0, 4, 512);

  // 9. final partials: K=4096 split 4x1024; nx=4, ny=64, nz=4 -> 1024 blocks
  gemm_kernel<M_FINAL><<<1024, 256, 0, stream>>>(
      out2, 1024, 4096, WoT, 1024, 4096, nullptr, Pf, 8192L * 512, 512, 4, 1024);

  // 10. reduce partials + bias -> fp32 out
  reduce4_kernel<<<4096, 256, 0, stream>>>(Pf, bo, outp);
}